// Round 7
// baseline (277.266 us; speedup 1.0000x reference)
//
#include <hip/hip_runtime.h>
#include <cstdint>
#include <cstddef>

// x[B=32, T=4096, N=256] fp32 -> z same shape.
// spike at t iff x>0 && t>=na; then na=t+6 (REFRACTORY_PERIOD=5).
#define BB 32
#define TT 4096
#define NN 256
#define NNV 64        // float4 groups per row
#define CC 32         // timesteps per chunk (one u32 bit-word)
#define PSUB 4        // chunks per block (one per 64-lane wave)
#define PP 128        // chunks per chain (TT/CC)
#define PG 32         // blocks per (batch) chain-group

// ---- Kernel A: pure streaming sign extraction (no state coupling) ----
__global__ __launch_bounds__(256, 4) void sign_extract(const float* __restrict__ x,
                                                       uint32_t* __restrict__ bits_g) {
    const int tid = threadIdx.x;
    const int pg = blockIdx.x >> 5;
    const int b  = blockIdx.x & 31;
    const int psub = tid >> 6;
    const int n4 = tid & 63;
    const int p = pg * PSUB + psub;

    const float4* __restrict__ xv = reinterpret_cast<const float4*>(x)
        + ((size_t)b * TT + (size_t)p * CC) * NNV + n4;

    uint32_t cur0 = 0, cur1 = 0, cur2 = 0, cur3 = 0;

    #pragma unroll
    for (int h = 0; h < 2; ++h) {          // two 16-deep load batches
        float4 buf[16];
        #pragma unroll
        for (int u = 0; u < 16; ++u)
            buf[u] = xv[(size_t)(h * 16 + u) * NNV];
        #pragma unroll
        for (int u = 0; u < 16; ++u) {
            const int j = h * 16 + u;
            cur0 |= (buf[u].x > 0.0f) ? (1u << j) : 0u;
            cur1 |= (buf[u].y > 0.0f) ? (1u << j) : 0u;
            cur2 |= (buf[u].z > 0.0f) ? (1u << j) : 0u;
            cur3 |= (buf[u].w > 0.0f) ? (1u << j) : 0u;
        }
    }

    const size_t row = (size_t)b * PP + p;
    reinterpret_cast<uint4*>(bits_g)[row * NNV + n4] =
        make_uint4(cur0, cur1, cur2, cur3);
}

// ---- Kernel B: per-chain trajectory walk, sign bits -> spike bits ----
// One thread per chain; ffs-jump over refractory gaps (<=6 spikes/word).
__global__ __launch_bounds__(64) void trajectory(const uint32_t* __restrict__ bits_g,
                                                 uint32_t* __restrict__ spk) {
    const int g = blockIdx.x * 64 + threadIdx.x;   // global chain id
    const int b = g >> 8;
    const int n = g & 255;

    int na = 0;  // next-allowed step, relative to current word start
    for (int pb = 0; pb < PP; pb += 16) {
        uint32_t w[16];
        #pragma unroll
        for (int i = 0; i < 16; ++i)               // independent, coalesced
            w[i] = bits_g[((size_t)b * PP + pb + i) * NN + n];
        #pragma unroll
        for (int i = 0; i < 16; ++i) {
            uint32_t s = 0;
            #pragma unroll
            for (int it = 0; it < 6; ++it) {       // max 6 spikes per 32 steps
                const uint32_t m =
                    (na < 32) ? (w[i] & (0xFFFFFFFFu << na)) : 0u;
                if (m) {
                    const int j = __builtin_ctz(m);
                    s |= (1u << j);
                    na = j + 6;
                }
            }
            spk[((size_t)b * PP + pb + i) * NN + n] = s;
            na -= 32;
            if (na < 0) na = 0;
        }
    }
}

// ---- Kernel C: pure streaming expand, spike bits -> fp32 z ----
__global__ __launch_bounds__(256, 4) void expand(const uint32_t* __restrict__ spk,
                                                 float* __restrict__ z) {
    const int tid = threadIdx.x;
    const int pg = blockIdx.x >> 5;
    const int b  = blockIdx.x & 31;
    const int psub = tid >> 6;
    const int n4 = tid & 63;
    const int p = pg * PSUB + psub;

    const size_t row = (size_t)b * PP + p;
    const uint4 sv = reinterpret_cast<const uint4*>(spk)[row * NNV + n4];
    const uint32_t w0 = sv.x, w1 = sv.y, w2 = sv.z, w3 = sv.w;

    float4* __restrict__ zv = reinterpret_cast<float4*>(z)
        + ((size_t)b * TT + (size_t)p * CC) * NNV + n4;

    #pragma unroll
    for (int j = 0; j < CC; ++j) {
        zv[(size_t)j * NNV] = make_float4(
            ((w0 >> j) & 1u) ? 1.0f : 0.0f,
            ((w1 >> j) & 1u) ? 1.0f : 0.0f,
            ((w2 >> j) & 1u) ? 1.0f : 0.0f,
            ((w3 >> j) & 1u) ? 1.0f : 0.0f);
    }
}

extern "C" void kernel_launch(void* const* d_in, const int* in_sizes, int n_in,
                              void* d_out, int out_size, void* d_ws, size_t ws_size,
                              hipStream_t stream) {
    const float* x = (const float*)d_in[0];
    float* z = (float*)d_out;

    // ws: sign bits 4 MiB | spike bits 4 MiB
    uint32_t* bits_g = (uint32_t*)d_ws;
    uint32_t* spk = (uint32_t*)((char*)d_ws + (size_t)BB * PP * NN * 4);

    sign_extract<<<dim3(BB * PG), 256, 0, stream>>>(x, bits_g);
    trajectory<<<dim3(BB * NN / 64), 64, 0, stream>>>(bits_g, spk);
    expand<<<dim3(BB * PG), 256, 0, stream>>>(spk, z);
}